// Round 13
// baseline (501.645 us; speedup 1.0000x reference)
//
#include <hip/hip_runtime.h>
#include <hip/hip_bf16.h>
#include <hip/hip_cooperative_groups.h>
#include <stdint.h>

namespace cg = cooperative_groups;

namespace {

constexpr int Hh    = 16;
constexpr int LL    = 4096;
constexpr int DD    = 64;
constexpr int BH    = 64;            // B*H
constexpr int CHUNK = 128;           // rows per tile
constexpr int NCH   = LL / CHUNK;    // 32 chunks per (b,h)
constexpr int RPT   = 8;             // rows per 16-lane team
constexpr int RECF  = 128;           // floats per record (64 k-sums | 64 kv-sums)
constexpr int TILEF = CHUNK * DD;    // 8192 floats per stream tile (32 KB)
constexpr int BPB   = 8;             // blocks per (b,h) in coop path
constexpr int NGEN  = NCH / BPB;     // 4 generations
constexpr int GRID  = BH * BPB;      // 512 blocks
constexpr float EPS = 1e-6f;

typedef __attribute__((ext_vector_type(4))) float f32x4;

__device__ __forceinline__ float elu1(float x) {
    return x > 0.0f ? x + 1.0f : __expf(x);
}

template<int CTRL>
__device__ __forceinline__ float dpp_xor_add(float x) {
    int yi = __builtin_amdgcn_update_dpp(0, __float_as_int(x), CTRL, 0xF, 0xF, true);
    return x + __int_as_float(yi);
}
template<int IMM>
__device__ __forceinline__ float swz_xor_add(float x) {
    int yi = __builtin_amdgcn_ds_swizzle(__float_as_int(x), IMM);
    return x + __int_as_float(yi);
}
__device__ __forceinline__ float team_sum16(float x) {
    x = dpp_xor_add<0xB1>(x);
    x = dpp_xor_add<0x4E>(x);
    x = swz_xor_add<0x101F>(x);
    x = swz_xor_add<0x201F>(x);
    return x;
}

typedef const __attribute__((address_space(1))) void* as1_t;
typedef __attribute__((address_space(3))) void* as3_t;
__device__ __forceinline__ void gload16(const void* g, void* l) {
    __builtin_amdgcn_global_load_lds((as1_t)g, (as3_t)l, 16, 0, 0);
}

// ============================================================================
// Fallback path (R11, proven 66.9 µs): pass1 -> scan -> pass2
// ============================================================================
__global__ __launch_bounds__(256) void la_pass1(
    const float* __restrict__ kp, const float* __restrict__ vp,
    const float* __restrict__ maskp, float* __restrict__ ws)
{
    const int blk  = blockIdx.x;
    const int bh   = blk >> 5;
    const int ch   = blk & (NCH - 1);
    const int b    = bh >> 4;
    const int t    = threadIdx.x;
    const int qd   = t & 15;
    const int team = t >> 4;
    const int wave = t >> 6;
    const int ln   = t & 63;

    const long base = ((long)bh * LL + (long)ch * CHUNK) * DD;
    const float* mrow = maskp + (long)b * LL + (long)ch * CHUNK + team * RPT;

    __shared__ __align__(16) float tileK[TILEF];
    __shared__ __align__(16) float tileV[TILEF];
    __shared__ float red[16][RECF];

    {
        const int woff = wave * 256;
        #pragma unroll
        for (int i = 0; i < 8; ++i)
            gload16(kp + base + i * 1024 + woff + ln * 4, &tileK[i * 1024 + woff]);
        #pragma unroll
        for (int i = 0; i < 8; ++i)
            gload16(vp + base + i * 1024 + woff + ln * 4, &tileV[i * 1024 + woff]);
    }

    float mv[RPT];
    #pragma unroll
    for (int r = 0; r < RPT; ++r) mv[r] = mrow[r];

    asm volatile("s_waitcnt vmcnt(0)" ::: "memory");
    __syncthreads();

    const int tbase = (team * RPT) * DD + qd * 4;
    float4 sk = make_float4(0.f, 0.f, 0.f, 0.f);
    float4 sv = make_float4(0.f, 0.f, 0.f, 0.f);
    #pragma unroll
    for (int r = 0; r < RPT; ++r) {
        const float4 k4 = *(const float4*)&tileK[tbase + r * DD];
        const float4 v4 = *(const float4*)&tileV[tbase + r * DD];
        const float  m  = mv[r];
        const float kf0 = elu1(k4.x) * m;
        const float kf1 = elu1(k4.y) * m;
        const float kf2 = elu1(k4.z) * m;
        const float kf3 = elu1(k4.w) * m;
        sk.x += kf0;              sk.y += kf1;
        sk.z += kf2;              sk.w += kf3;
        sv.x += kf0 * (v4.x * m); sv.y += kf1 * (v4.y * m);
        sv.z += kf2 * (v4.z * m); sv.w += kf3 * (v4.w * m);
    }

    red[team][qd*4+0] = sk.x; red[team][qd*4+1] = sk.y;
    red[team][qd*4+2] = sk.z; red[team][qd*4+3] = sk.w;
    red[team][64+qd*4+0] = sv.x; red[team][64+qd*4+1] = sv.y;
    red[team][64+qd*4+2] = sv.z; red[team][64+qd*4+3] = sv.w;
    __syncthreads();

    if (t < RECF) {
        float acc = 0.f;
        #pragma unroll
        for (int i = 0; i < 16; ++i) acc += red[i][t];
        ws[((long)bh * NCH + ch) * RECF + t] = acc;
    }
}

__global__ __launch_bounds__(RECF) void la_scan(float* __restrict__ ws)
{
    const int bh = blockIdx.x;
    const int t  = threadIdx.x;
    float* wb = ws + (long)bh * NCH * RECF + t;

    float vals[NCH];
    #pragma unroll
    for (int c = 0; c < NCH; ++c) vals[c] = wb[(long)c * RECF];

    float acc = 0.f;
    #pragma unroll
    for (int c = 0; c < NCH; ++c) {
        const float x = vals[c];
        wb[(long)c * RECF] = acc;
        acc += x;
    }
}

__global__ __launch_bounds__(256) void la_pass2(
    const float* __restrict__ qp, const float* __restrict__ kp,
    const float* __restrict__ vp, const float* __restrict__ maskp,
    const float* __restrict__ ws, float* __restrict__ outp)
{
    const int blk  = blockIdx.x;
    const int bh   = blk >> 5;
    const int ch   = blk & (NCH - 1);
    const int b    = bh >> 4;
    const int t    = threadIdx.x;
    const int qd   = t & 15;
    const int team = t >> 4;
    const int wave = t >> 6;
    const int ln   = t & 63;

    const long base  = ((long)bh * LL + (long)ch * CHUNK) * DD;
    const long rbase = base + (long)team * RPT * DD + qd * 4;
    const float* mrow = maskp + (long)b * LL + (long)ch * CHUNK + team * RPT;

    __shared__ __align__(16) float tileK[TILEF];
    __shared__ __align__(16) float tileV[TILEF];
    __shared__ float red[16][RECF];

    {
        const int woff = wave * 256;
        #pragma unroll
        for (int i = 0; i < 8; ++i)
            gload16(kp + base + i * 1024 + woff + ln * 4, &tileK[i * 1024 + woff]);
        #pragma unroll
        for (int i = 0; i < 8; ++i)
            gload16(vp + base + i * 1024 + woff + ln * 4, &tileV[i * 1024 + woff]);
    }

    const float* rec = ws + ((long)bh * NCH + ch) * RECF;
    const float4 ck = *(const float4*)(rec + qd * 4);
    const float4 cv = *(const float4*)(rec + 64 + qd * 4);

    float mv[RPT];
    #pragma unroll
    for (int r = 0; r < RPT; ++r) mv[r] = mrow[r];

    float4 qb[RPT];
    #pragma unroll
    for (int r = 0; r < RPT; ++r)
        qb[r] = *(const float4*)(qp + rbase + (long)r * DD);

    asm volatile("s_waitcnt vmcnt(0)" ::: "memory");
    __syncthreads();

    const int tbase = (team * RPT) * DD + qd * 4;
    float4 tk = make_float4(0.f, 0.f, 0.f, 0.f);
    float4 tv = make_float4(0.f, 0.f, 0.f, 0.f);
    #pragma unroll
    for (int r = 0; r < RPT; ++r) {
        const float4 k4 = *(const float4*)&tileK[tbase + r * DD];
        const float4 v4 = *(const float4*)&tileV[tbase + r * DD];
        const float  m  = mv[r];
        const float kf0 = elu1(k4.x) * m;
        const float kf1 = elu1(k4.y) * m;
        const float kf2 = elu1(k4.z) * m;
        const float kf3 = elu1(k4.w) * m;
        tk.x += kf0;              tk.y += kf1;
        tk.z += kf2;              tk.w += kf3;
        tv.x += kf0 * (v4.x * m); tv.y += kf1 * (v4.y * m);
        tv.z += kf2 * (v4.z * m); tv.w += kf3 * (v4.w * m);
    }

    red[team][qd*4+0] = tk.x; red[team][qd*4+1] = tk.y;
    red[team][qd*4+2] = tk.z; red[team][qd*4+3] = tk.w;
    red[team][64+qd*4+0] = tv.x; red[team][64+qd*4+1] = tv.y;
    red[team][64+qd*4+2] = tv.z; red[team][64+qd*4+3] = tv.w;
    __syncthreads();

    if (t < RECF) {
        float acc = 0.f;
        #pragma unroll
        for (int i = 0; i < 16; ++i) {
            const float x = red[i][t];
            red[i][t] = acc;
            acc += x;
        }
    }
    __syncthreads();

    float4 rk, rv;
    rk.x = ck.x + red[team][qd*4+0]; rk.y = ck.y + red[team][qd*4+1];
    rk.z = ck.z + red[team][qd*4+2]; rk.w = ck.w + red[team][qd*4+3];
    rv.x = cv.x + red[team][64+qd*4+0]; rv.y = cv.y + red[team][64+qd*4+1];
    rv.z = cv.z + red[team][64+qd*4+2]; rv.w = cv.w + red[team][64+qd*4+3];

    #pragma unroll
    for (int r = 0; r < RPT; ++r) {
        const float4 k4 = *(const float4*)&tileK[tbase + r * DD];
        const float4 v4 = *(const float4*)&tileV[tbase + r * DD];
        const float  m  = mv[r];
        const float kf0 = elu1(k4.x) * m;
        const float kf1 = elu1(k4.y) * m;
        const float kf2 = elu1(k4.z) * m;
        const float kf3 = elu1(k4.w) * m;
        rk.x += kf0;              rk.y += kf1;
        rk.z += kf2;              rk.w += kf3;
        rv.x += kf0 * (v4.x * m); rv.y += kf1 * (v4.y * m);
        rv.z += kf2 * (v4.z * m); rv.w += kf3 * (v4.w * m);

        float4 qf;
        qf.x = elu1(qb[r].x); qf.y = elu1(qb[r].y);
        qf.z = elu1(qb[r].z); qf.w = elu1(qb[r].w);

        float pz = qf.x*rk.x + qf.y*rk.y + qf.z*rk.z + qf.w*rk.w;
        pz = team_sum16(pz);

        const float z   = (pz + EPS) * m;
        const float inv = __builtin_amdgcn_rcpf(z);

        f32x4 o;
        o.x = qf.x * rv.x * inv;
        o.y = qf.y * rv.y * inv;
        o.z = qf.z * rv.z * inv;
        o.w = qf.w * rv.w * inv;
        __builtin_nontemporal_store(o, (f32x4*)(outp + rbase + (long)r * DD));
    }
}

// ============================================================================
// Cooperative single-read path (R12 logic, launch now error-checked on host).
// ============================================================================
__global__ __launch_bounds__(256, 2) void la_coop(
    const float* __restrict__ qp, const float* __restrict__ kp,
    const float* __restrict__ vp, const float* __restrict__ maskp,
    float* __restrict__ records, float* __restrict__ outp)
{
    cg::grid_group grid = cg::this_grid();

    const int bid  = blockIdx.x;
    const int bh   = bid >> 3;
    const int j    = bid & (BPB - 1);
    const int b    = bh >> 4;
    const int t    = threadIdx.x;
    const int qd   = t & 15;
    const int team = t >> 4;
    const int wave = t >> 6;
    const int ln   = t & 63;

    __shared__ __align__(16) float tileK[TILEF];
    __shared__ __align__(16) float tileV[TILEF];
    __shared__ float red[16][RECF];
    __shared__ float carry_lds[RECF];

    float carry = 0.f;

    for (int g = 0; g < NGEN; ++g) {
        const int ch = g * BPB + j;
        const long base  = ((long)bh * LL + (long)ch * CHUNK) * DD;
        const long rbase = base + (long)team * RPT * DD + qd * 4;
        const float* mrow = maskp + (long)b * LL + (long)ch * CHUNK + team * RPT;

        {
            const int woff = wave * 256;
            #pragma unroll
            for (int i = 0; i < 8; ++i)
                gload16(kp + base + i * 1024 + woff + ln * 4, &tileK[i * 1024 + woff]);
            #pragma unroll
            for (int i = 0; i < 8; ++i)
                gload16(vp + base + i * 1024 + woff + ln * 4, &tileV[i * 1024 + woff]);
        }

        float mv[RPT];
        #pragma unroll
        for (int r = 0; r < RPT; ++r) mv[r] = mrow[r];

        float4 qb[RPT];
        #pragma unroll
        for (int r = 0; r < RPT; ++r)
            qb[r] = *(const float4*)(qp + rbase + (long)r * DD);

        asm volatile("s_waitcnt vmcnt(0)" ::: "memory");
        __syncthreads();

        const int tbase = (team * RPT) * DD + qd * 4;
        float4 tk = make_float4(0.f, 0.f, 0.f, 0.f);
        float4 tv = make_float4(0.f, 0.f, 0.f, 0.f);
        #pragma unroll
        for (int r = 0; r < RPT; ++r) {
            const float4 k4 = *(const float4*)&tileK[tbase + r * DD];
            const float4 v4 = *(const float4*)&tileV[tbase + r * DD];
            const float  m  = mv[r];
            const float kf0 = elu1(k4.x) * m;
            const float kf1 = elu1(k4.y) * m;
            const float kf2 = elu1(k4.z) * m;
            const float kf3 = elu1(k4.w) * m;
            tk.x += kf0;              tk.y += kf1;
            tk.z += kf2;              tk.w += kf3;
            tv.x += kf0 * (v4.x * m); tv.y += kf1 * (v4.y * m);
            tv.z += kf2 * (v4.z * m); tv.w += kf3 * (v4.w * m);
        }

        red[team][qd*4+0] = tk.x; red[team][qd*4+1] = tk.y;
        red[team][qd*4+2] = tk.z; red[team][qd*4+3] = tk.w;
        red[team][64+qd*4+0] = tv.x; red[team][64+qd*4+1] = tv.y;
        red[team][64+qd*4+2] = tv.z; red[team][64+qd*4+3] = tv.w;
        __syncthreads();

        if (t < RECF) {
            float acc = 0.f;
            #pragma unroll
            for (int i = 0; i < 16; ++i) {
                const float x = red[i][t];
                red[i][t] = acc;
                acc += x;
            }
            __hip_atomic_store(&records[((long)bh * NCH + ch) * RECF + t], acc,
                               __ATOMIC_RELAXED, __HIP_MEMORY_SCOPE_AGENT);
        }
        __syncthreads();
        __threadfence();
        grid.sync();

        if (t < RECF) {
            const int start = (g == 0) ? 0 : ch - BPB;
            float p[BPB];
            #pragma unroll
            for (int s = 0; s < BPB; ++s) {
                const int c = start + s;
                p[s] = (c < ch)
                     ? __hip_atomic_load(&records[((long)bh * NCH + c) * RECF + t],
                                         __ATOMIC_RELAXED, __HIP_MEMORY_SCOPE_AGENT)
                     : 0.f;
            }
            carry += ((((((p[0]+p[1])+p[2])+p[3])+p[4])+p[5])+p[6])+p[7];
            carry_lds[t] = carry;
        }
        __syncthreads();

        float4 rk, rv;
        rk.x = carry_lds[qd*4+0] + red[team][qd*4+0];
        rk.y = carry_lds[qd*4+1] + red[team][qd*4+1];
        rk.z = carry_lds[qd*4+2] + red[team][qd*4+2];
        rk.w = carry_lds[qd*4+3] + red[team][qd*4+3];
        rv.x = carry_lds[64+qd*4+0] + red[team][64+qd*4+0];
        rv.y = carry_lds[64+qd*4+1] + red[team][64+qd*4+1];
        rv.z = carry_lds[64+qd*4+2] + red[team][64+qd*4+2];
        rv.w = carry_lds[64+qd*4+3] + red[team][64+qd*4+3];

        #pragma unroll
        for (int r = 0; r < RPT; ++r) {
            const float4 k4 = *(const float4*)&tileK[tbase + r * DD];
            const float4 v4 = *(const float4*)&tileV[tbase + r * DD];
            const float  m  = mv[r];
            const float kf0 = elu1(k4.x) * m;
            const float kf1 = elu1(k4.y) * m;
            const float kf2 = elu1(k4.z) * m;
            const float kf3 = elu1(k4.w) * m;
            rk.x += kf0;              rk.y += kf1;
            rk.z += kf2;              rk.w += kf3;
            rv.x += kf0 * (v4.x * m); rv.y += kf1 * (v4.y * m);
            rv.z += kf2 * (v4.z * m); rv.w += kf3 * (v4.w * m);

            float4 qf;
            qf.x = elu1(qb[r].x); qf.y = elu1(qb[r].y);
            qf.z = elu1(qb[r].z); qf.w = elu1(qb[r].w);

            float pz = qf.x*rk.x + qf.y*rk.y + qf.z*rk.z + qf.w*rk.w;
            pz = team_sum16(pz);

            const float z   = (pz + EPS) * m;
            const float inv = __builtin_amdgcn_rcpf(z);

            f32x4 o;
            o.x = qf.x * rv.x * inv;
            o.y = qf.y * rv.y * inv;
            o.z = qf.z * rv.z * inv;
            o.w = qf.w * rv.w * inv;
            __builtin_nontemporal_store(o, (f32x4*)(outp + rbase + (long)r * DD));
        }
        __syncthreads();
    }
}

} // namespace

extern "C" void kernel_launch(void* const* d_in, const int* in_sizes, int n_in,
                              void* d_out, int out_size, void* d_ws, size_t ws_size,
                              hipStream_t stream) {
    const float* q    = (const float*)d_in[0];
    const float* k    = (const float*)d_in[1];
    const float* v    = (const float*)d_in[2];
    const float* mask = (const float*)d_in[3];
    float* out = (float*)d_out;
    float* ws  = (float*)d_ws;   // 1 MiB records, fully written-before-read each call

    void* args[] = { (void*)&q, (void*)&k, (void*)&v, (void*)&mask,
                     (void*)&ws, (void*)&out };
    hipError_t e = hipLaunchCooperativeKernel((const void*)la_coop, dim3(GRID),
                                              dim3(256), args, 0, stream);
    if (e != hipSuccess) {
        // proven R11 path (66.9 µs)
        la_pass1<<<dim3(BH * NCH), dim3(256), 0, stream>>>(k, v, mask, ws);
        la_scan <<<dim3(BH),       dim3(RECF), 0, stream>>>(ws);
        la_pass2<<<dim3(BH * NCH), dim3(256), 0, stream>>>(q, k, v, mask, ws, out);
    }
}

// Round 14
// 66.582 us; speedup vs baseline: 7.5342x; 7.5342x over previous
//
#include <hip/hip_runtime.h>
#include <hip/hip_bf16.h>
#include <stdint.h>

namespace {

constexpr int Hh    = 16;
constexpr int LL    = 4096;
constexpr int DD    = 64;
constexpr int BH    = 64;            // B*H
constexpr int CHUNK = 128;           // rows per block
constexpr int NCH   = LL / CHUNK;    // 32 chunks per (b,h)
constexpr int RPT   = 8;             // rows per 16-lane team
constexpr int RECF  = 128;           // floats per ws record (64 k-sums | 64 kv-sums)
constexpr int TILEF = CHUNK * DD;    // 8192 floats per stream tile (32 KB)
constexpr float EPS = 1e-6f;

typedef __attribute__((ext_vector_type(4))) float f32x4;

__device__ __forceinline__ float elu1(float x) {
    return x > 0.0f ? x + 1.0f : __expf(x);
}

// --- 16-lane team butterfly sum ---
template<int CTRL>
__device__ __forceinline__ float dpp_xor_add(float x) {
    int yi = __builtin_amdgcn_update_dpp(0, __float_as_int(x), CTRL, 0xF, 0xF, true);
    return x + __int_as_float(yi);
}
template<int IMM>
__device__ __forceinline__ float swz_xor_add(float x) {
    int yi = __builtin_amdgcn_ds_swizzle(__float_as_int(x), IMM);
    return x + __int_as_float(yi);
}
__device__ __forceinline__ float team_sum16(float x) {
    x = dpp_xor_add<0xB1>(x);
    x = dpp_xor_add<0x4E>(x);
    x = swz_xor_add<0x101F>(x);
    x = swz_xor_add<0x201F>(x);
    return x;
}

// --- async global->LDS 16B: global src PER-LANE, LDS dest wave-uniform ---
typedef const __attribute__((address_space(1))) void* as1_t;
typedef __attribute__((address_space(3))) void* as3_t;
__device__ __forceinline__ void gload16(const void* g, void* l) {
    __builtin_amdgcn_global_load_lds((as1_t)g, (as3_t)l, 16, 0, 0);
}

// ============================================================================
// Pass 1: k,v chunk tile -> LDS via global_load_lds (zero VGPR in-flight),
// one drain, team totals from LDS, in-block reduce -> ws[bh*NCH+ch][128].
// ============================================================================
__global__ __launch_bounds__(256) void la_pass1(
    const float* __restrict__ kp, const float* __restrict__ vp,
    const float* __restrict__ maskp, float* __restrict__ ws)
{
    const int blk  = blockIdx.x;
    const int bh   = blk >> 5;
    const int ch   = blk & (NCH - 1);
    const int b    = bh >> 4;
    const int t    = threadIdx.x;
    const int qd   = t & 15;
    const int team = t >> 4;
    const int wave = t >> 6;
    const int ln   = t & 63;

    const long base = ((long)bh * LL + (long)ch * CHUNK) * DD;
    const float* mrow = maskp + (long)b * LL + (long)ch * CHUNK + team * RPT;

    __shared__ __align__(16) float tileK[TILEF];
    __shared__ __align__(16) float tileV[TILEF];
    __shared__ float red[16][RECF];

    {
        const int woff = wave * 256;
        #pragma unroll
        for (int i = 0; i < 8; ++i)
            gload16(kp + base + i * 1024 + woff + ln * 4, &tileK[i * 1024 + woff]);
        #pragma unroll
        for (int i = 0; i < 8; ++i)
            gload16(vp + base + i * 1024 + woff + ln * 4, &tileV[i * 1024 + woff]);
    }

    float mv[RPT];
    #pragma unroll
    for (int r = 0; r < RPT; ++r) mv[r] = mrow[r];

    asm volatile("s_waitcnt vmcnt(0)" ::: "memory");
    __syncthreads();

    const int tbase = (team * RPT) * DD + qd * 4;
    float4 sk = make_float4(0.f, 0.f, 0.f, 0.f);
    float4 sv = make_float4(0.f, 0.f, 0.f, 0.f);
    #pragma unroll
    for (int r = 0; r < RPT; ++r) {
        const float4 k4 = *(const float4*)&tileK[tbase + r * DD];
        const float4 v4 = *(const float4*)&tileV[tbase + r * DD];
        const float  m  = mv[r];
        const float kf0 = elu1(k4.x) * m;
        const float kf1 = elu1(k4.y) * m;
        const float kf2 = elu1(k4.z) * m;
        const float kf3 = elu1(k4.w) * m;
        sk.x += kf0;              sk.y += kf1;
        sk.z += kf2;              sk.w += kf3;
        sv.x += kf0 * (v4.x * m); sv.y += kf1 * (v4.y * m);
        sv.z += kf2 * (v4.z * m); sv.w += kf3 * (v4.w * m);
    }

    red[team][qd*4+0] = sk.x; red[team][qd*4+1] = sk.y;
    red[team][qd*4+2] = sk.z; red[team][qd*4+3] = sk.w;
    red[team][64+qd*4+0] = sv.x; red[team][64+qd*4+1] = sv.y;
    red[team][64+qd*4+2] = sv.z; red[team][64+qd*4+3] = sv.w;
    __syncthreads();

    if (t < RECF) {
        float acc = 0.f;
        #pragma unroll
        for (int i = 0; i < 16; ++i) acc += red[i][t];
        ws[((long)bh * NCH + ch) * RECF + t] = acc;
    }
}

// ============================================================================
// Pass 1.5: in-place exclusive scan of the NCH chunk-total records per (b,h).
// ============================================================================
__global__ __launch_bounds__(RECF) void la_scan(float* __restrict__ ws)
{
    const int bh = blockIdx.x;
    const int t  = threadIdx.x;
    float* wb = ws + (long)bh * NCH * RECF + t;

    float vals[NCH];
    #pragma unroll
    for (int c = 0; c < NCH; ++c) vals[c] = wb[(long)c * RECF];

    float acc = 0.f;
    #pragma unroll
    for (int c = 0; c < NCH; ++c) {
        const float x = vals[c];
        wb[(long)c * RECF] = acc;
        acc += x;
    }
}

// ============================================================================
// Pass 2: DMA k,v tiles to LDS, q burst draining under the DMA, team totals,
// in-place team scan, serial 8-row scan + nontemporal output.
// ============================================================================
__global__ __launch_bounds__(256) void la_pass2(
    const float* __restrict__ qp, const float* __restrict__ kp,
    const float* __restrict__ vp, const float* __restrict__ maskp,
    const float* __restrict__ ws, float* __restrict__ outp)
{
    const int blk  = blockIdx.x;
    const int bh   = blk >> 5;
    const int ch   = blk & (NCH - 1);
    const int b    = bh >> 4;
    const int t    = threadIdx.x;
    const int qd   = t & 15;
    const int team = t >> 4;
    const int wave = t >> 6;
    const int ln   = t & 63;

    const long base  = ((long)bh * LL + (long)ch * CHUNK) * DD;
    const long rbase = base + (long)team * RPT * DD + qd * 4;
    const float* mrow = maskp + (long)b * LL + (long)ch * CHUNK + team * RPT;

    __shared__ __align__(16) float tileK[TILEF];
    __shared__ __align__(16) float tileV[TILEF];
    __shared__ float red[16][RECF];

    {
        const int woff = wave * 256;
        #pragma unroll
        for (int i = 0; i < 8; ++i)
            gload16(kp + base + i * 1024 + woff + ln * 4, &tileK[i * 1024 + woff]);
        #pragma unroll
        for (int i = 0; i < 8; ++i)
            gload16(vp + base + i * 1024 + woff + ln * 4, &tileV[i * 1024 + woff]);
    }

    const float* rec = ws + ((long)bh * NCH + ch) * RECF;
    const float4 ck = *(const float4*)(rec + qd * 4);
    const float4 cv = *(const float4*)(rec + 64 + qd * 4);

    float mv[RPT];
    #pragma unroll
    for (int r = 0; r < RPT; ++r) mv[r] = mrow[r];

    float4 qb[RPT];
    #pragma unroll
    for (int r = 0; r < RPT; ++r)
        qb[r] = *(const float4*)(qp + rbase + (long)r * DD);

    asm volatile("s_waitcnt vmcnt(0)" ::: "memory");
    __syncthreads();

    const int tbase = (team * RPT) * DD + qd * 4;
    float4 tk = make_float4(0.f, 0.f, 0.f, 0.f);
    float4 tv = make_float4(0.f, 0.f, 0.f, 0.f);
    #pragma unroll
    for (int r = 0; r < RPT; ++r) {
        const float4 k4 = *(const float4*)&tileK[tbase + r * DD];
        const float4 v4 = *(const float4*)&tileV[tbase + r * DD];
        const float  m  = mv[r];
        const float kf0 = elu1(k4.x) * m;
        const float kf1 = elu1(k4.y) * m;
        const float kf2 = elu1(k4.z) * m;
        const float kf3 = elu1(k4.w) * m;
        tk.x += kf0;              tk.y += kf1;
        tk.z += kf2;              tk.w += kf3;
        tv.x += kf0 * (v4.x * m); tv.y += kf1 * (v4.y * m);
        tv.z += kf2 * (v4.z * m); tv.w += kf3 * (v4.w * m);
    }

    red[team][qd*4+0] = tk.x; red[team][qd*4+1] = tk.y;
    red[team][qd*4+2] = tk.z; red[team][qd*4+3] = tk.w;
    red[team][64+qd*4+0] = tv.x; red[team][64+qd*4+1] = tv.y;
    red[team][64+qd*4+2] = tv.z; red[team][64+qd*4+3] = tv.w;
    __syncthreads();

    if (t < RECF) {
        float acc = 0.f;
        #pragma unroll
        for (int i = 0; i < 16; ++i) {
            const float x = red[i][t];
            red[i][t] = acc;
            acc += x;
        }
    }
    __syncthreads();

    float4 rk, rv;
    rk.x = ck.x + red[team][qd*4+0]; rk.y = ck.y + red[team][qd*4+1];
    rk.z = ck.z + red[team][qd*4+2]; rk.w = ck.w + red[team][qd*4+3];
    rv.x = cv.x + red[team][64+qd*4+0]; rv.y = cv.y + red[team][64+qd*4+1];
    rv.z = cv.z + red[team][64+qd*4+2]; rv.w = cv.w + red[team][64+qd*4+3];

    #pragma unroll
    for (int r = 0; r < RPT; ++r) {
        const float4 k4 = *(const float4*)&tileK[tbase + r * DD];
        const float4 v4 = *(const float4*)&tileV[tbase + r * DD];
        const float  m  = mv[r];
        const float kf0 = elu1(k4.x) * m;
        const float kf1 = elu1(k4.y) * m;
        const float kf2 = elu1(k4.z) * m;
        const float kf3 = elu1(k4.w) * m;
        rk.x += kf0;              rk.y += kf1;
        rk.z += kf2;              rk.w += kf3;
        rv.x += kf0 * (v4.x * m); rv.y += kf1 * (v4.y * m);
        rv.z += kf2 * (v4.z * m); rv.w += kf3 * (v4.w * m);

        float4 qf;
        qf.x = elu1(qb[r].x); qf.y = elu1(qb[r].y);
        qf.z = elu1(qb[r].z); qf.w = elu1(qb[r].w);

        float pz = qf.x*rk.x + qf.y*rk.y + qf.z*rk.z + qf.w*rk.w;
        pz = team_sum16(pz);

        const float z   = (pz + EPS) * m;
        const float inv = __builtin_amdgcn_rcpf(z);

        f32x4 o;
        o.x = qf.x * rv.x * inv;
        o.y = qf.y * rv.y * inv;
        o.z = qf.z * rv.z * inv;
        o.w = qf.w * rv.w * inv;
        __builtin_nontemporal_store(o, (f32x4*)(outp + rbase + (long)r * DD));
    }
}

} // namespace

extern "C" void kernel_launch(void* const* d_in, const int* in_sizes, int n_in,
                              void* d_out, int out_size, void* d_ws, size_t ws_size,
                              hipStream_t stream) {
    const float* q    = (const float*)d_in[0];
    const float* k    = (const float*)d_in[1];
    const float* v    = (const float*)d_in[2];
    const float* mask = (const float*)d_in[3];
    float* out = (float*)d_out;
    float* ws  = (float*)d_ws;   // needs BH*NCH*RECF floats = 1 MiB

    la_pass1<<<dim3(BH * NCH), dim3(256), 0, stream>>>(k, v, mask, ws);
    la_scan <<<dim3(BH),       dim3(RECF), 0, stream>>>(ws);
    la_pass2<<<dim3(BH * NCH), dim3(256), 0, stream>>>(q, k, v, mask, ws, out);
}